// Round 4
// baseline (462.037 us; speedup 1.0000x reference)
//
#include <hip/hip_runtime.h>
#include <math.h>

#define NN 32768
#define NE 524288
#define RSTR 32   // record stride in floats (128 B, cache-line aligned)
#define SREC_STR 36  // LDS record stride (floats): 4*r mod 32 tiles banks

// overflow-safe softplus(x) - ln2 using HW exp2/log2 (v_exp_f32 / v_log_f32)
__device__ __forceinline__ float sspf(float x) {
    const float INVLN2 = 1.4426950408889634f;
    const float LN2    = 0.69314718055994530942f;
    float t = __builtin_amdgcn_exp2f(-fabsf(x) * INVLN2);
    return fmaxf(x, 0.0f) + LN2 * __builtin_amdgcn_logf(1.0f + t) - LN2;
}

// ---------------- CSR build ----------------
// rank[e] = arrival order of edge e within its segment (atomic return).
__global__ __launch_bounds__(256) void hist_kernel(
    const int* __restrict__ idx_i, int* __restrict__ counts, int* __restrict__ rank)
{
    int e = blockIdx.x * 256 + threadIdx.x;
    rank[e] = atomicAdd(&counts[idx_i[e]], 1);
}

// single block, 1024 threads, 32 counts each; writes start[0..NN]
__global__ __launch_bounds__(1024) void scan_kernel(
    const int* __restrict__ counts, int* __restrict__ start)
{
    __shared__ int tmp[1024];
    int tid = threadIdx.x;
    int base = tid * 32;
    int local[32];
    int sum = 0;
    const int4* c4 = (const int4*)(counts + base);
#pragma unroll
    for (int q = 0; q < 8; q++) {
        int4 v = c4[q];
        local[q*4+0] = sum; sum += v.x;
        local[q*4+1] = sum; sum += v.y;
        local[q*4+2] = sum; sum += v.z;
        local[q*4+3] = sum; sum += v.w;
    }
    tmp[tid] = sum;
    __syncthreads();
    for (int off = 1; off < 1024; off <<= 1) {
        int v = 0;
        if (tid >= off) v = tmp[tid - off];
        __syncthreads();
        if (tid >= off) tmp[tid] += v;
        __syncthreads();
    }
    int excl = tmp[tid] - sum;
#pragma unroll
    for (int k = 0; k < 32; k++) {
        start[base + k] = excl + local[k];
    }
    if (tid == 1023) start[NN] = tmp[1023];
}

// ---------------- pack: fused fill + filter-MLP-layer-1 ----------------
// record (32 floats = one 128B line): [0:16)=h*rc, [16:20)=Yr, [20]=rc,
// [21]=j(bits), [22:32)=zero pad.
// Wave-cooperative scatter: records staged in LDS, then 8 lanes emit the 8
// float4 quarters of ONE record per store instruction -> each instruction
// writes 8 complete 128B lines (vs 64 partial lines in the naive scatter).
__global__ __launch_bounds__(256) void pack_kernel(
    const float* __restrict__ f_ij,     // (E,32)
    const float* __restrict__ rcut_ij,  // (E,)
    const float* __restrict__ Yr,       // (E,4)
    const int*   __restrict__ idx_i,
    const int*   __restrict__ idx_j,
    const float* __restrict__ mW1,      // (32,16)
    const float* __restrict__ mb1,      // (16,)
    const int*   __restrict__ start,    // (N+1,)
    const int*   __restrict__ rank,     // (E,)
    float* __restrict__ epack)
{
    __shared__ float sW1[512];
    __shared__ float sb1[16];
    __shared__ float srec[256 * SREC_STR];  // 36 KB
    __shared__ int   sslot[256];
    int t = threadIdx.x;
    for (int k = t; k < 512; k += 256) sW1[k] = mW1[k];
    if (t < 16) sb1[t] = mb1[t];
    __syncthreads();

    int e = blockIdx.x * 256 + t;
    float h[16];
#pragma unroll
    for (int f = 0; f < 16; f++) h[f] = sb1[f];
    const float4* frow = (const float4*)(f_ij + (size_t)e * 32);
#pragma unroll
    for (int rq = 0; rq < 8; rq++) {
        float4 fv = frow[rq];
        int r = rq * 4;
#pragma unroll
        for (int f = 0; f < 16; f++)
            h[f] += fv.x * sW1[(r+0)*16+f] + fv.y * sW1[(r+1)*16+f]
                  + fv.z * sW1[(r+2)*16+f] + fv.w * sW1[(r+3)*16+f];
    }
    float rc = rcut_ij[e];
#pragma unroll
    for (int f = 0; f < 16; f++) h[f] = sspf(h[f]) * rc;

    int i = idx_i[e];
    int j = idx_j[e];
    float4 y = ((const float4*)Yr)[e];
    int slot = start[i] + rank[e];

    // stage record in LDS
    float* rp = srec + t * SREC_STR;
    float4* rp4 = (float4*)rp;
#pragma unroll
    for (int q = 0; q < 4; q++) rp4[q] = ((float4*)h)[q];
    rp4[4] = y;
    float4 tail; tail.x = rc; tail.y = __int_as_float(j); tail.z = 0.f; tail.w = 0.f;
    rp4[5] = tail;
    float4 z; z.x = 0.f; z.y = 0.f; z.z = 0.f; z.w = 0.f;
    rp4[6] = z;
    rp4[7] = z;
    sslot[t] = slot;
    __syncthreads();

    // cooperative write: per instruction, lanes 0-7 cover record r0, lanes
    // 8-15 record r0+1, ... -> 8 full 128B lines per global_store_dwordx4.
    int lane = t & 63;
    int wbase = t & 192;          // wave's record base within block
    int qi = lane & 7;            // float4 quarter within record
#pragma unroll
    for (int g = 0; g < 8; g++) {
        int r = wbase + g * 8 + (lane >> 3);
        int s = sslot[r];
        float4 v = ((const float4*)(srec + r * SREC_STR))[qi];
        ((float4*)(epack + (size_t)s * RSTR))[qi] = v;
    }
}

// ---------------- node embedding ----------------
// interleaved output layout: embed[n*64 + f*4 + {0,1,2,3}] = {s1, v1x, v1y, v1z}
// so nodeagg fetches one float4 per (edge, lane).
__global__ __launch_bounds__(256) void embed_kernel(
    const float* __restrict__ x,
    const float* __restrict__ W1s,   // (64,16)
    const float* __restrict__ W1v,   // (32,16)
    float* __restrict__ embed)
{
    __shared__ float sWs[1024];
    __shared__ float sWv[512];
    int t = threadIdx.x;
    for (int k = t; k < 1024; k += 256) sWs[k] = W1s[k];
    for (int k = t; k < 512;  k += 256) sWv[k] = W1v[k];
    __syncthreads();

    int n = blockIdx.x * 256 + t;
    const float* xr = x + (size_t)n * 160;

    float s1[16];
#pragma unroll
    for (int f = 0; f < 16; f++) s1[f] = 0.f;
#pragma unroll
    for (int cq = 0; cq < 16; cq++) {
        float4 sv = ((const float4*)xr)[cq];
        int c = cq * 4;
#pragma unroll
        for (int f = 0; f < 16; f++) {
            s1[f] += sv.x * sWs[(c+0)*16+f] + sv.y * sWs[(c+1)*16+f]
                   + sv.z * sWs[(c+2)*16+f] + sv.w * sWs[(c+3)*16+f];
        }
    }

    float v1[48];
#pragma unroll
    for (int k = 0; k < 48; k++) v1[k] = 0.f;
#pragma unroll
    for (int q = 0; q < 24; q++) {
        float4 vv = ((const float4*)(xr + 64))[q];
        float vals[4] = {vv.x, vv.y, vv.z, vv.w};
#pragma unroll
        for (int u = 0; u < 4; u++) {
            int m = q * 4 + u;
            int c = m / 3, d = m % 3;
            float val = vals[u];
#pragma unroll
            for (int f = 0; f < 16; f++)
                v1[f*3+d] += val * sWv[c*16+f];
        }
    }

    float ob[64];
    const float is32 = 0.17677669529663688f;
#pragma unroll
    for (int f = 0; f < 16; f++) {
        ob[f*4+0] = s1[f] * 0.125f;
        ob[f*4+1] = v1[f*3+0] * is32;
        ob[f*4+2] = v1[f*3+1] * is32;
        ob[f*4+3] = v1[f*3+2] * is32;
    }

    float4* eo = (float4*)(embed + (size_t)n * 64);
#pragma unroll
    for (int q = 0; q < 16; q++) eo[q] = ((float4*)ob)[q];
}

// ---------------- node-centric aggregation ----------------
// ONE WAVE PER NODE. Lane c in [0,64) owns output column c of the edge-MLP:
// grp=c>>4 selects {w0a,w0b,w1a,w1b}, f=c&15. Weights (16) live in registers
// -> zero LDS in the inner loop. Record loads are wave-uniform broadcasts
// (1 line). Embed gather is one float4/lane. Both software-pipelined 1-deep.
// acc planar layout per node (unchanged):
// [0:16)=n0a, [16:32)=n0b, [32:48)=n1a_x, [48:64)=n1a_y, [64:80)=n1a_z,
// [80:96)=n1b_x, [96:112)=n1b_y, [112:128)=n1b_z
__global__ __launch_bounds__(256) void nodeagg_kernel(
    const float* __restrict__ embed,   // (N,64) interleaved (f*4+{s,x,y,z})
    const float* __restrict__ epack,   // (E,RSTR) CSR-ordered records
    const int*   __restrict__ start,   // (N+1,)
    const float* __restrict__ mW2,     // (16,96)
    const float* __restrict__ mb2,     // (96,)
    float* __restrict__ acc)           // (N,128) planar
{
    int t = threadIdx.x;
    int lane = t & 63;
    int node = (blockIdx.x * 256 + t) >> 6;
    int grp = lane >> 4;
    int f = lane & 15;

    float wk[16];
#pragma unroll
    for (int k = 0; k < 16; k++) wk[k] = mW2[k * 96 + lane];
    float bias = mb2[lane];

    // loop-invariant group predicates
    bool gs  = (grp == 0) || (grp == 2);   // scalar-source lanes (use sj)
    bool g1  = (grp == 1);
    bool g2  = (grp == 2);
    bool g3  = (grp == 3);
    bool g23 = (grp >= 2);

    float A0 = 0.f, A1 = 0.f, A2 = 0.f;

    int s0 = start[node];
    int s1 = start[node + 1];

    if (s0 < s1) {
        const float4* r4 = (const float4*)(epack + (size_t)s0 * RSTR);
        float4 h0 = r4[0], h1 = r4[1], h2 = r4[2], h3 = r4[3];
        float4 y  = r4[4], tl = r4[5];
        float4 e4 = ((const float4*)(embed +
                     (size_t)__float_as_int(tl.y) * 64))[f];

#define NAGG_COMPUTE()                                                      \
        {                                                                   \
            float w = tl.x * bias;                                          \
            w += h0.x*wk[0]  + h0.y*wk[1]  + h0.z*wk[2]  + h0.w*wk[3];      \
            w += h1.x*wk[4]  + h1.y*wk[5]  + h1.z*wk[6]  + h1.w*wk[7];      \
            w += h2.x*wk[8]  + h2.y*wk[9]  + h2.z*wk[10] + h2.w*wk[11];     \
            w += h3.x*wk[12] + h3.y*wk[13] + h3.z*wk[14] + h3.w*wk[15];     \
            float sj = e4.x, vx = e4.y, vy = e4.z, vz = e4.w;               \
            float a0 = gs ? sj : vx;                                        \
            float a1 = g2 ? sj : vy;                                        \
            float a2 = g2 ? sj : vz;                                        \
            float c0 = (g1 || g2) ? y.y : y.x;                              \
            float c1 = g3 ? y.x : y.z;                                      \
            float c2 = g3 ? y.x : y.w;                                      \
            float t0 = a0 * c0, t1 = a1 * c1, t2 = a2 * c2;                 \
            float m0 = g1 ? (t0 + t1 + t2) : t0;                            \
            float m1 = g23 ? t1 : 0.f;                                      \
            float m2 = g23 ? t2 : 0.f;                                      \
            A0 += w * m0;                                                   \
            A1 += w * m1;                                                   \
            A2 += w * m2;                                                   \
        }

        for (int q = s0; q < s1 - 1; q++) {
            const float4* n4 = (const float4*)(epack + (size_t)(q + 1) * RSTR);
            float4 nh0 = n4[0], nh1 = n4[1], nh2 = n4[2], nh3 = n4[3];
            float4 ny  = n4[4], ntl = n4[5];

            NAGG_COMPUTE();

            float4 ne4 = ((const float4*)(embed +
                          (size_t)__float_as_int(ntl.y) * 64))[f];
            h0 = nh0; h1 = nh1; h2 = nh2; h3 = nh3;
            y = ny; tl = ntl; e4 = ne4;
        }
        NAGG_COMPUTE();
#undef NAGG_COMPUTE
    }

    const float is3 = 0.5773502691896258f;   // 1/sqrt(3)
    float* o = acc + (size_t)node * 128;
    if (grp == 0) {
        o[f] = A0;
    } else if (grp == 1) {
        o[16 + f] = A0 * is3;
    } else if (grp == 2) {
        o[32 + f] = A0; o[48 + f] = A1; o[64 + f] = A2;
    } else {
        o[80 + f] = A0; o[96 + f] = A1; o[112 + f] = A2;
    }
}

// ---------------- node output ----------------
// 64 nodes per block (lane = node), 4 wave-specialized roles:
// wave 0: s-chain cols 0-31; wave 1: s-chain cols 32-63
// wave 2: v-chain (d=0 all cols, d=1 cols 0-15); wave 3: (d=1 cols 16-31, d=2 all)
// Weight columns are wave-uniform (readfirstlane) -> scalar s_load broadcasts.
// Intermediates in LDS with +1 pad (2-way bank alias only, free).

__device__ __forceinline__ void v2_seg32(const float* a, int d, int cb,
    const float* __restrict__ W2v, float* V2, int ln)
{
    cb = __builtin_amdgcn_readfirstlane(cb);
    const float is32 = 0.17677669529663688f;
    float na[16], nb[16];
    const float4* pa = (const float4*)(a + 32 + 16*d);
    const float4* pb = (const float4*)(a + 80 + 16*d);
#pragma unroll
    for (int q = 0; q < 4; q++) { ((float4*)na)[q] = pa[q]; ((float4*)nb)[q] = pb[q]; }
    float tacc[32];
#pragma unroll
    for (int c = 0; c < 32; c++) tacc[c] = 0.f;
#pragma unroll
    for (int f = 0; f < 16; f++) {
        float fa = na[f], fb = nb[f];
#pragma unroll
        for (int c = 0; c < 32; c++)
            tacc[c] += fa * W2v[f*32 + cb + c] + fb * W2v[(16+f)*32 + cb + c];
    }
    float* row = V2 + (d*64 + ln) * 33 + cb;
#pragma unroll
    for (int c = 0; c < 32; c++) row[c] = tacc[c] * is32;
}

__device__ __forceinline__ void v2_seg16(const float* a, int d, int cb,
    const float* __restrict__ W2v, float* V2, int ln)
{
    cb = __builtin_amdgcn_readfirstlane(cb);
    const float is32 = 0.17677669529663688f;
    float na[16], nb[16];
    const float4* pa = (const float4*)(a + 32 + 16*d);
    const float4* pb = (const float4*)(a + 80 + 16*d);
#pragma unroll
    for (int q = 0; q < 4; q++) { ((float4*)na)[q] = pa[q]; ((float4*)nb)[q] = pb[q]; }
    float tacc[16];
#pragma unroll
    for (int c = 0; c < 16; c++) tacc[c] = 0.f;
#pragma unroll
    for (int f = 0; f < 16; f++) {
        float fa = na[f], fb = nb[f];
#pragma unroll
        for (int c = 0; c < 16; c++)
            tacc[c] += fa * W2v[f*32 + cb + c] + fb * W2v[(16+f)*32 + cb + c];
    }
    float* row = V2 + (d*64 + ln) * 33 + cb;
#pragma unroll
    for (int c = 0; c < 16; c++) row[c] = tacc[c] * is32;
}

__device__ __forceinline__ void v3_seg32(float* o, int d, int cb,
    const float* __restrict__ W3v, const float* V2, int ln)
{
    cb = __builtin_amdgcn_readfirstlane(cb);
    const float is32 = 0.17677669529663688f;
    float tacc[32];
#pragma unroll
    for (int c = 0; c < 32; c++) tacc[c] = 0.f;
    const float* row = V2 + (d*64 + ln) * 33;
#pragma unroll
    for (int k = 0; k < 32; k++) {
        float vk = row[k];
#pragma unroll
        for (int c = 0; c < 32; c++) tacc[c] += vk * W3v[k*32 + cb + c];
    }
#pragma unroll
    for (int c = 0; c < 32; c++) o[64 + (cb+c)*3 + d] = tacc[c] * is32;
}

__device__ __forceinline__ void v3_seg16(float* o, int d, int cb,
    const float* __restrict__ W3v, const float* V2, int ln)
{
    cb = __builtin_amdgcn_readfirstlane(cb);
    const float is32 = 0.17677669529663688f;
    float tacc[16];
#pragma unroll
    for (int c = 0; c < 16; c++) tacc[c] = 0.f;
    const float* row = V2 + (d*64 + ln) * 33;
#pragma unroll
    for (int k = 0; k < 32; k++) {
        float vk = row[k];
#pragma unroll
        for (int c = 0; c < 16; c++) tacc[c] += vk * W3v[k*32 + cb + c];
    }
#pragma unroll
    for (int c = 0; c < 16; c++) o[64 + (cb+c)*3 + d] = tacc[c] * is32;
}

__global__ __launch_bounds__(256) void out_kernel(
    const float* __restrict__ acc,      // (N,128) planar
    const float* __restrict__ W2s,      // (32,64)
    const float* __restrict__ W2v,      // (32,32)
    const float* __restrict__ W3s,      // (64,64)
    const float* __restrict__ W3v,      // (32,32)
    float* __restrict__ out)            // (N,160)
{
    __shared__ float S2[64*65];   // S2[ln*65 + c], c<64
    __shared__ float V2[3*64*33]; // V2[(d*64+ln)*33 + c], c<32
    int t = threadIdx.x;
    int w = t >> 6, ln = t & 63;
    int node = blockIdx.x * 64 + ln;
    const float* a = acc + (size_t)node * 128;
    float* o = out + (size_t)node * 160;
    const float is32 = 0.17677669529663688f;

    if (w < 2) {
        int cb = __builtin_amdgcn_readfirstlane(w * 32);
        float n0r[32];
#pragma unroll
        for (int q = 0; q < 8; q++) ((float4*)n0r)[q] = ((const float4*)a)[q];
        float tacc[32];
#pragma unroll
        for (int c = 0; c < 32; c++) tacc[c] = 0.f;
#pragma unroll
        for (int k = 0; k < 32; k++) {
            float nk = n0r[k];
#pragma unroll
            for (int c = 0; c < 32; c++) tacc[c] += nk * W2s[k*64 + cb + c];
        }
        float* row = S2 + ln*65 + cb;
#pragma unroll
        for (int c = 0; c < 32; c++) row[c] = sspf(tacc[c] * is32);
    } else if (w == 2) {
        v2_seg32(a, 0, 0,  W2v, V2, ln);
        v2_seg16(a, 1, 0,  W2v, V2, ln);
    } else {
        v2_seg16(a, 1, 16, W2v, V2, ln);
        v2_seg32(a, 2, 0,  W2v, V2, ln);
    }
    __syncthreads();
    if (w < 2) {
        int cb = __builtin_amdgcn_readfirstlane(w * 32);
        float tacc[32];
#pragma unroll
        for (int c = 0; c < 32; c++) tacc[c] = 0.f;
        const float* row = S2 + ln*65;
#pragma unroll
        for (int k = 0; k < 64; k++) {
            float sk = row[k];
#pragma unroll
            for (int c = 0; c < 32; c++) tacc[c] += sk * W3s[k*64 + cb + c];
        }
#pragma unroll
        for (int q = 0; q < 8; q++) {
            float4 r = {tacc[q*4+0]*0.125f, tacc[q*4+1]*0.125f,
                        tacc[q*4+2]*0.125f, tacc[q*4+3]*0.125f};
            ((float4*)(o + cb))[q] = r;
        }
    } else if (w == 2) {
        v3_seg32(o, 0, 0,  W3v, V2, ln);
        v3_seg16(o, 1, 0,  W3v, V2, ln);
    } else {
        v3_seg16(o, 1, 16, W3v, V2, ln);
        v3_seg32(o, 2, 0,  W3v, V2, ln);
    }
}

extern "C" void kernel_launch(void* const* d_in, const int* in_sizes, int n_in,
                              void* d_out, int out_size, void* d_ws, size_t ws_size,
                              hipStream_t stream) {
    const float* x     = (const float*)d_in[0];
    const float* f_ij  = (const float*)d_in[1];
    const float* rcut  = (const float*)d_in[2];
    const float* Yr    = (const float*)d_in[3];
    const float* W1s   = (const float*)d_in[4];
    const float* W1v   = (const float*)d_in[5];
    const float* mW1   = (const float*)d_in[6];
    const float* mb1   = (const float*)d_in[7];
    const float* mW2   = (const float*)d_in[8];
    const float* mb2   = (const float*)d_in[9];
    const float* W2s   = (const float*)d_in[10];
    const float* W2v   = (const float*)d_in[11];
    const float* W3s   = (const float*)d_in[12];
    const float* W3v   = (const float*)d_in[13];
    const int*   idx_i = (const int*)d_in[14];
    const int*   idx_j = (const int*)d_in[15];
    float* out = (float*)d_out;

    // workspace layout (floats)
    float* fws   = (float*)d_ws;
    float* embed = fws;                                  // N*64
    float* acc   = embed + (size_t)NN * 64;              // N*128
    float* epack = acc   + (size_t)NN * 128;             // E*RSTR
    int* ibase   = (int*)(epack + (size_t)NE * RSTR);
    int* counts  = ibase;                                // N
    int* start   = counts + NN;                          // N+1
    int* rank    = start + NN + 1;                       // E

    hipMemsetAsync(counts, 0, (size_t)NN * sizeof(int), stream);
    hist_kernel<<<NE/256, 256, 0, stream>>>(idx_i, counts, rank);
    scan_kernel<<<1, 1024, 0, stream>>>(counts, start);
    pack_kernel<<<NE/256, 256, 0, stream>>>(f_ij, rcut, Yr, idx_i, idx_j,
                                            mW1, mb1, start, rank, epack);
    embed_kernel<<<NN/256, 256, 0, stream>>>(x, W1s, W1v, embed);
    nodeagg_kernel<<<(NN*64)/256, 256, 0, stream>>>(embed, epack, start, mW2, mb2, acc);
    out_kernel<<<NN/64, 256, 0, stream>>>(acc, W2s, W2v, W3s, W3v, out);
}

// Round 5
// 415.236 us; speedup vs baseline: 1.1127x; 1.1127x over previous
//
#include <hip/hip_runtime.h>
#include <math.h>

#define NN 32768
#define NE 524288
#define RSTR 32   // record stride in floats (128 B, cache-line aligned)
#define SREC_STR 36  // LDS record stride (floats): 4*r mod 32 tiles banks

// overflow-safe softplus(x) - ln2 using HW exp2/log2 (v_exp_f32 / v_log_f32)
__device__ __forceinline__ float sspf(float x) {
    const float INVLN2 = 1.4426950408889634f;
    const float LN2    = 0.69314718055994530942f;
    float t = __builtin_amdgcn_exp2f(-fabsf(x) * INVLN2);
    return fmaxf(x, 0.0f) + LN2 * __builtin_amdgcn_logf(1.0f + t) - LN2;
}

// ---------------- CSR build ----------------
// rank[e] = arrival order of edge e within its segment (atomic return).
__global__ __launch_bounds__(256) void hist_kernel(
    const int* __restrict__ idx_i, int* __restrict__ counts, int* __restrict__ rank)
{
    int e = blockIdx.x * 256 + threadIdx.x;
    rank[e] = atomicAdd(&counts[idx_i[e]], 1);
}

// single block, 1024 threads, 32 counts each; writes start[0..NN]
__global__ __launch_bounds__(1024) void scan_kernel(
    const int* __restrict__ counts, int* __restrict__ start)
{
    __shared__ int tmp[1024];
    int tid = threadIdx.x;
    int base = tid * 32;
    int local[32];
    int sum = 0;
    const int4* c4 = (const int4*)(counts + base);
#pragma unroll
    for (int q = 0; q < 8; q++) {
        int4 v = c4[q];
        local[q*4+0] = sum; sum += v.x;
        local[q*4+1] = sum; sum += v.y;
        local[q*4+2] = sum; sum += v.z;
        local[q*4+3] = sum; sum += v.w;
    }
    tmp[tid] = sum;
    __syncthreads();
    for (int off = 1; off < 1024; off <<= 1) {
        int v = 0;
        if (tid >= off) v = tmp[tid - off];
        __syncthreads();
        if (tid >= off) tmp[tid] += v;
        __syncthreads();
    }
    int excl = tmp[tid] - sum;
#pragma unroll
    for (int k = 0; k < 32; k++) {
        start[base + k] = excl + local[k];
    }
    if (tid == 1023) start[NN] = tmp[1023];
}

// ---------------- pack: fused fill + filter-MLP-layer-1 ----------------
// record (32 floats = one 128B line): [0:16)=h*rc, [16:20)=Yr, [20]=rc,
// [21]=j(bits), [22:32)=zero pad.
// Wave-cooperative scatter: records staged in LDS, then 8 lanes emit the 8
// float4 quarters of ONE record per store instruction -> each instruction
// writes 8 complete 128B lines (vs 64 partial lines in the naive scatter).
__global__ __launch_bounds__(256) void pack_kernel(
    const float* __restrict__ f_ij,     // (E,32)
    const float* __restrict__ rcut_ij,  // (E,)
    const float* __restrict__ Yr,       // (E,4)
    const int*   __restrict__ idx_i,
    const int*   __restrict__ idx_j,
    const float* __restrict__ mW1,      // (32,16)
    const float* __restrict__ mb1,      // (16,)
    const int*   __restrict__ start,    // (N+1,)
    const int*   __restrict__ rank,     // (E,)
    float* __restrict__ epack)
{
    __shared__ float sW1[512];
    __shared__ float sb1[16];
    __shared__ float srec[256 * SREC_STR];  // 36 KB
    __shared__ int   sslot[256];
    int t = threadIdx.x;
    for (int k = t; k < 512; k += 256) sW1[k] = mW1[k];
    if (t < 16) sb1[t] = mb1[t];
    __syncthreads();

    int e = blockIdx.x * 256 + t;
    float h[16];
#pragma unroll
    for (int f = 0; f < 16; f++) h[f] = sb1[f];
    const float4* frow = (const float4*)(f_ij + (size_t)e * 32);
#pragma unroll
    for (int rq = 0; rq < 8; rq++) {
        float4 fv = frow[rq];
        int r = rq * 4;
#pragma unroll
        for (int f = 0; f < 16; f++)
            h[f] += fv.x * sW1[(r+0)*16+f] + fv.y * sW1[(r+1)*16+f]
                  + fv.z * sW1[(r+2)*16+f] + fv.w * sW1[(r+3)*16+f];
    }
    float rc = rcut_ij[e];
#pragma unroll
    for (int f = 0; f < 16; f++) h[f] = sspf(h[f]) * rc;

    int i = idx_i[e];
    int j = idx_j[e];
    float4 y = ((const float4*)Yr)[e];
    int slot = start[i] + rank[e];

    // stage record in LDS
    float* rp = srec + t * SREC_STR;
    float4* rp4 = (float4*)rp;
#pragma unroll
    for (int q = 0; q < 4; q++) rp4[q] = ((float4*)h)[q];
    rp4[4] = y;
    float4 tail; tail.x = rc; tail.y = __int_as_float(j); tail.z = 0.f; tail.w = 0.f;
    rp4[5] = tail;
    float4 z; z.x = 0.f; z.y = 0.f; z.z = 0.f; z.w = 0.f;
    rp4[6] = z;
    rp4[7] = z;
    sslot[t] = slot;
    __syncthreads();

    // cooperative write: per instruction, lanes 0-7 cover record r0, lanes
    // 8-15 record r0+1, ... -> 8 full 128B lines per global_store_dwordx4.
    int lane = t & 63;
    int wbase = t & 192;          // wave's record base within block
    int qi = lane & 7;            // float4 quarter within record
#pragma unroll
    for (int g = 0; g < 8; g++) {
        int r = wbase + g * 8 + (lane >> 3);
        int s = sslot[r];
        float4 v = ((const float4*)(srec + r * SREC_STR))[qi];
        ((float4*)(epack + (size_t)s * RSTR))[qi] = v;
    }
}

// ---------------- node embedding ----------------
// interleaved output layout: embed[n*64 + f*4 + {0,1,2,3}] = {s1, v1x, v1y, v1z}
// so nodeagg fetches one float4 per (edge, lane).
// Staging loops are CHUNKED (#pragma unroll 1) to cap live registers:
// peak regs ~= s1(16)+v1(48)+chunk staging(<=24)+misc -> ~4 waves/SIMD.
__global__ __launch_bounds__(256) void embed_kernel(
    const float* __restrict__ x,
    const float* __restrict__ W1s,   // (64,16)
    const float* __restrict__ W1v,   // (32,16)
    float* __restrict__ embed)
{
    __shared__ float sWs[1024];
    __shared__ float sWv[512];
    int t = threadIdx.x;
    for (int k = t; k < 1024; k += 256) sWs[k] = W1s[k];
    for (int k = t; k < 512;  k += 256) sWv[k] = W1v[k];
    __syncthreads();

    int n = blockIdx.x * 256 + t;
    const float* xr = x + (size_t)n * 160;

    float s1[16];
#pragma unroll
    for (int f = 0; f < 16; f++) s1[f] = 0.f;
#pragma unroll 1
    for (int cc = 0; cc < 4; cc++) {
        float4 sv[4];
#pragma unroll
        for (int q = 0; q < 4; q++) sv[q] = ((const float4*)xr)[cc*4 + q];
#pragma unroll
        for (int q = 0; q < 4; q++) {
            int c = (cc*4 + q) * 4;
#pragma unroll
            for (int f = 0; f < 16; f++) {
                s1[f] += sv[q].x * sWs[(c+0)*16+f] + sv[q].y * sWs[(c+1)*16+f]
                       + sv[q].z * sWs[(c+2)*16+f] + sv[q].w * sWs[(c+3)*16+f];
            }
        }
    }

    float v1[48];
#pragma unroll
    for (int k = 0; k < 48; k++) v1[k] = 0.f;
    // 96 vector components = 4 chunks x 24 (= 8 columns x 3 dims each chunk)
#pragma unroll 1
    for (int cc = 0; cc < 4; cc++) {
        float4 vv[6];
#pragma unroll
        for (int q = 0; q < 6; q++) vv[q] = ((const float4*)(xr + 64))[cc*6 + q];
#pragma unroll
        for (int q = 0; q < 6; q++) {
            float vals[4] = {vv[q].x, vv[q].y, vv[q].z, vv[q].w};
#pragma unroll
            for (int u = 0; u < 4; u++) {
                int ml = q * 4 + u;         // 0..23, static
                int c = cc * 8 + ml / 3;    // runtime base + static
                int d = ml % 3;             // static
                float val = vals[u];
#pragma unroll
                for (int f = 0; f < 16; f++)
                    v1[f*3+d] += val * sWv[c*16+f];
            }
        }
    }

    float ob[64];
    const float is32 = 0.17677669529663688f;
#pragma unroll
    for (int f = 0; f < 16; f++) {
        ob[f*4+0] = s1[f] * 0.125f;
        ob[f*4+1] = v1[f*3+0] * is32;
        ob[f*4+2] = v1[f*3+1] * is32;
        ob[f*4+3] = v1[f*3+2] * is32;
    }

    float4* eo = (float4*)(embed + (size_t)n * 64);
#pragma unroll
    for (int q = 0; q < 16; q++) eo[q] = ((float4*)ob)[q];
}

// ---------------- node-centric aggregation ----------------
// TWO NODES PER WAVE. Lane c in [0,64) owns output column c of the edge-MLP:
// grp=c>>4 selects {w0a,w0b,w1a,w1b}, f=c&15. The 16 weight registers depend
// only on lane, so they are shared across nodes. Per iteration both nodes'
// record loads (wave-uniform broadcasts) are issued together, then both
// embed gathers, then both computes -> 2 independent memory chains per wave
// at ~4 waves/SIMD occupancy.
__global__ __launch_bounds__(256) void nodeagg_kernel(
    const float* __restrict__ embed,   // (N,64) interleaved (f*4+{s,x,y,z})
    const float* __restrict__ epack,   // (E,RSTR) CSR-ordered records
    const int*   __restrict__ start,   // (N+1,)
    const float* __restrict__ mW2,     // (16,96)
    const float* __restrict__ mb2,     // (96,)
    float* __restrict__ acc)           // (N,128) planar
{
    int t = threadIdx.x;
    int lane = t & 63;
    int wv = blockIdx.x * 4 + (t >> 6);
    int node0 = wv * 2;
    int grp = lane >> 4;
    int f = lane & 15;

    float wk[16];
#pragma unroll
    for (int k = 0; k < 16; k++) wk[k] = mW2[k * 96 + lane];
    float bias = mb2[lane];

    // loop-invariant group predicates
    bool gs  = (grp == 0) || (grp == 2);   // scalar-source lanes (use sj)
    bool g1  = (grp == 1);
    bool g2  = (grp == 2);
    bool g3  = (grp == 3);
    bool g23 = (grp >= 2);

    int sA = start[node0];
    int sB = start[node0 + 1];
    int sC = start[node0 + 2];
    int cntA = sB - sA, cntB = sC - sB;
    int maxc = cntA > cntB ? cntA : cntB;

    float A0a=0.f, A1a=0.f, A2a=0.f;
    float A0b=0.f, A1b=0.f, A2b=0.f;

#define NAGG_COMPUTE(H0,H1,H2,H3,Y,TL,E4,ACT,R0,R1,R2)                      \
        {                                                                   \
            float w = TL.x * bias;                                          \
            w += H0.x*wk[0]  + H0.y*wk[1]  + H0.z*wk[2]  + H0.w*wk[3];      \
            w += H1.x*wk[4]  + H1.y*wk[5]  + H1.z*wk[6]  + H1.w*wk[7];      \
            w += H2.x*wk[8]  + H2.y*wk[9]  + H2.z*wk[10] + H2.w*wk[11];     \
            w += H3.x*wk[12] + H3.y*wk[13] + H3.z*wk[14] + H3.w*wk[15];     \
            float sj = E4.x, vx = E4.y, vy = E4.z, vz = E4.w;               \
            float a0 = gs ? sj : vx;                                        \
            float a1 = g2 ? sj : vy;                                        \
            float a2 = g2 ? sj : vz;                                        \
            float c0 = (g1 || g2) ? Y.y : Y.x;                              \
            float c1 = g3 ? Y.x : Y.z;                                      \
            float c2 = g3 ? Y.x : Y.w;                                      \
            float t0 = a0 * c0, t1 = a1 * c1, t2 = a2 * c2;                 \
            float m0 = g1 ? (t0 + t1 + t2) : t0;                            \
            float m1 = g23 ? t1 : 0.f;                                      \
            float m2 = g23 ? t2 : 0.f;                                      \
            if (ACT) { R0 += w * m0; R1 += w * m1; R2 += w * m2; }          \
        }

    for (int it = 0; it < maxc; ++it) {
        bool actA = it < cntA;
        bool actB = it < cntB;
        int qa = actA ? (sA + it) : 0;
        int qb = actB ? (sB + it) : 0;
        const float4* ra = (const float4*)(epack + (size_t)qa * RSTR);
        const float4* rb = (const float4*)(epack + (size_t)qb * RSTR);
        // phase 1: both records (uniform broadcasts)
        float4 ah0 = ra[0], ah1 = ra[1], ah2 = ra[2], ah3 = ra[3];
        float4 ay  = ra[4], atl = ra[5];
        float4 bh0 = rb[0], bh1 = rb[1], bh2 = rb[2], bh3 = rb[3];
        float4 by  = rb[4], btl = rb[5];
        // phase 2: both gathers
        float4 ae4 = ((const float4*)(embed +
                      (size_t)__float_as_int(atl.y) * 64))[f];
        float4 be4 = ((const float4*)(embed +
                      (size_t)__float_as_int(btl.y) * 64))[f];
        // phase 3: compute both
        NAGG_COMPUTE(ah0, ah1, ah2, ah3, ay, atl, ae4, actA, A0a, A1a, A2a);
        NAGG_COMPUTE(bh0, bh1, bh2, bh3, by, btl, be4, actB, A0b, A1b, A2b);
    }
#undef NAGG_COMPUTE

    const float is3 = 0.5773502691896258f;   // 1/sqrt(3)
    float* oa = acc + (size_t)node0 * 128;
    float* ob = acc + (size_t)(node0 + 1) * 128;
    if (grp == 0) {
        oa[f] = A0a;               ob[f] = A0b;
    } else if (grp == 1) {
        oa[16 + f] = A0a * is3;    ob[16 + f] = A0b * is3;
    } else if (grp == 2) {
        oa[32 + f] = A0a; oa[48 + f] = A1a; oa[64 + f] = A2a;
        ob[32 + f] = A0b; ob[48 + f] = A1b; ob[64 + f] = A2b;
    } else {
        oa[80 + f] = A0a; oa[96 + f] = A1a; oa[112 + f] = A2a;
        ob[80 + f] = A0b; ob[96 + f] = A1b; ob[112 + f] = A2b;
    }
}

// ---------------- node output ----------------
// 64 nodes per block (lane = node), 4 wave-specialized roles:
// wave 0: s-chain cols 0-31; wave 1: s-chain cols 32-63
// wave 2: v-chain (d=0 all cols, d=1 cols 0-15); wave 3: (d=1 cols 16-31, d=2 all)
// Weight columns are wave-uniform (readfirstlane) -> scalar s_load broadcasts.
// Intermediates in LDS with +1 pad (2-way bank alias only, free).

__device__ __forceinline__ void v2_seg32(const float* a, int d, int cb,
    const float* __restrict__ W2v, float* V2, int ln)
{
    cb = __builtin_amdgcn_readfirstlane(cb);
    const float is32 = 0.17677669529663688f;
    float na[16], nb[16];
    const float4* pa = (const float4*)(a + 32 + 16*d);
    const float4* pb = (const float4*)(a + 80 + 16*d);
#pragma unroll
    for (int q = 0; q < 4; q++) { ((float4*)na)[q] = pa[q]; ((float4*)nb)[q] = pb[q]; }
    float tacc[32];
#pragma unroll
    for (int c = 0; c < 32; c++) tacc[c] = 0.f;
#pragma unroll
    for (int f = 0; f < 16; f++) {
        float fa = na[f], fb = nb[f];
#pragma unroll
        for (int c = 0; c < 32; c++)
            tacc[c] += fa * W2v[f*32 + cb + c] + fb * W2v[(16+f)*32 + cb + c];
    }
    float* row = V2 + (d*64 + ln) * 33 + cb;
#pragma unroll
    for (int c = 0; c < 32; c++) row[c] = tacc[c] * is32;
}

__device__ __forceinline__ void v2_seg16(const float* a, int d, int cb,
    const float* __restrict__ W2v, float* V2, int ln)
{
    cb = __builtin_amdgcn_readfirstlane(cb);
    const float is32 = 0.17677669529663688f;
    float na[16], nb[16];
    const float4* pa = (const float4*)(a + 32 + 16*d);
    const float4* pb = (const float4*)(a + 80 + 16*d);
#pragma unroll
    for (int q = 0; q < 4; q++) { ((float4*)na)[q] = pa[q]; ((float4*)nb)[q] = pb[q]; }
    float tacc[16];
#pragma unroll
    for (int c = 0; c < 16; c++) tacc[c] = 0.f;
#pragma unroll
    for (int f = 0; f < 16; f++) {
        float fa = na[f], fb = nb[f];
#pragma unroll
        for (int c = 0; c < 16; c++)
            tacc[c] += fa * W2v[f*32 + cb + c] + fb * W2v[(16+f)*32 + cb + c];
    }
    float* row = V2 + (d*64 + ln) * 33 + cb;
#pragma unroll
    for (int c = 0; c < 16; c++) row[c] = tacc[c] * is32;
}

__device__ __forceinline__ void v3_seg32(float* o, int d, int cb,
    const float* __restrict__ W3v, const float* V2, int ln)
{
    cb = __builtin_amdgcn_readfirstlane(cb);
    const float is32 = 0.17677669529663688f;
    float tacc[32];
#pragma unroll
    for (int c = 0; c < 32; c++) tacc[c] = 0.f;
    const float* row = V2 + (d*64 + ln) * 33;
#pragma unroll
    for (int k = 0; k < 32; k++) {
        float vk = row[k];
#pragma unroll
        for (int c = 0; c < 32; c++) tacc[c] += vk * W3v[k*32 + cb + c];
    }
#pragma unroll
    for (int c = 0; c < 32; c++) o[64 + (cb+c)*3 + d] = tacc[c] * is32;
}

__device__ __forceinline__ void v3_seg16(float* o, int d, int cb,
    const float* __restrict__ W3v, const float* V2, int ln)
{
    cb = __builtin_amdgcn_readfirstlane(cb);
    const float is32 = 0.17677669529663688f;
    float tacc[16];
#pragma unroll
    for (int c = 0; c < 16; c++) tacc[c] = 0.f;
    const float* row = V2 + (d*64 + ln) * 33;
#pragma unroll
    for (int k = 0; k < 32; k++) {
        float vk = row[k];
#pragma unroll
        for (int c = 0; c < 16; c++) tacc[c] += vk * W3v[k*32 + cb + c];
    }
#pragma unroll
    for (int c = 0; c < 16; c++) o[64 + (cb+c)*3 + d] = tacc[c] * is32;
}

__global__ __launch_bounds__(256) void out_kernel(
    const float* __restrict__ acc,      // (N,128) planar
    const float* __restrict__ W2s,      // (32,64)
    const float* __restrict__ W2v,      // (32,32)
    const float* __restrict__ W3s,      // (64,64)
    const float* __restrict__ W3v,      // (32,32)
    float* __restrict__ out)            // (N,160)
{
    __shared__ float S2[64*65];   // S2[ln*65 + c], c<64
    __shared__ float V2[3*64*33]; // V2[(d*64+ln)*33 + c], c<32
    int t = threadIdx.x;
    int w = t >> 6, ln = t & 63;
    int node = blockIdx.x * 64 + ln;
    const float* a = acc + (size_t)node * 128;
    float* o = out + (size_t)node * 160;
    const float is32 = 0.17677669529663688f;

    if (w < 2) {
        int cb = __builtin_amdgcn_readfirstlane(w * 32);
        float n0r[32];
#pragma unroll
        for (int q = 0; q < 8; q++) ((float4*)n0r)[q] = ((const float4*)a)[q];
        float tacc[32];
#pragma unroll
        for (int c = 0; c < 32; c++) tacc[c] = 0.f;
#pragma unroll
        for (int k = 0; k < 32; k++) {
            float nk = n0r[k];
#pragma unroll
            for (int c = 0; c < 32; c++) tacc[c] += nk * W2s[k*64 + cb + c];
        }
        float* row = S2 + ln*65 + cb;
#pragma unroll
        for (int c = 0; c < 32; c++) row[c] = sspf(tacc[c] * is32);
    } else if (w == 2) {
        v2_seg32(a, 0, 0,  W2v, V2, ln);
        v2_seg16(a, 1, 0,  W2v, V2, ln);
    } else {
        v2_seg16(a, 1, 16, W2v, V2, ln);
        v2_seg32(a, 2, 0,  W2v, V2, ln);
    }
    __syncthreads();
    if (w < 2) {
        int cb = __builtin_amdgcn_readfirstlane(w * 32);
        float tacc[32];
#pragma unroll
        for (int c = 0; c < 32; c++) tacc[c] = 0.f;
        const float* row = S2 + ln*65;
#pragma unroll
        for (int k = 0; k < 64; k++) {
            float sk = row[k];
#pragma unroll
            for (int c = 0; c < 32; c++) tacc[c] += sk * W3s[k*64 + cb + c];
        }
#pragma unroll
        for (int q = 0; q < 8; q++) {
            float4 r = {tacc[q*4+0]*0.125f, tacc[q*4+1]*0.125f,
                        tacc[q*4+2]*0.125f, tacc[q*4+3]*0.125f};
            ((float4*)(o + cb))[q] = r;
        }
    } else if (w == 2) {
        v3_seg32(o, 0, 0,  W3v, V2, ln);
        v3_seg16(o, 1, 0,  W3v, V2, ln);
    } else {
        v3_seg16(o, 1, 16, W3v, V2, ln);
        v3_seg32(o, 2, 0,  W3v, V2, ln);
    }
}

extern "C" void kernel_launch(void* const* d_in, const int* in_sizes, int n_in,
                              void* d_out, int out_size, void* d_ws, size_t ws_size,
                              hipStream_t stream) {
    const float* x     = (const float*)d_in[0];
    const float* f_ij  = (const float*)d_in[1];
    const float* rcut  = (const float*)d_in[2];
    const float* Yr    = (const float*)d_in[3];
    const float* W1s   = (const float*)d_in[4];
    const float* W1v   = (const float*)d_in[5];
    const float* mW1   = (const float*)d_in[6];
    const float* mb1   = (const float*)d_in[7];
    const float* mW2   = (const float*)d_in[8];
    const float* mb2   = (const float*)d_in[9];
    const float* W2s   = (const float*)d_in[10];
    const float* W2v   = (const float*)d_in[11];
    const float* W3s   = (const float*)d_in[12];
    const float* W3v   = (const float*)d_in[13];
    const int*   idx_i = (const int*)d_in[14];
    const int*   idx_j = (const int*)d_in[15];
    float* out = (float*)d_out;

    // workspace layout (floats)
    float* fws   = (float*)d_ws;
    float* embed = fws;                                  // N*64
    float* acc   = embed + (size_t)NN * 64;              // N*128
    float* epack = acc   + (size_t)NN * 128;             // E*RSTR
    int* ibase   = (int*)(epack + (size_t)NE * RSTR);
    int* counts  = ibase;                                // N
    int* start   = counts + NN;                          // N+1
    int* rank    = start + NN + 1;                       // E

    hipMemsetAsync(counts, 0, (size_t)NN * sizeof(int), stream);
    hist_kernel<<<NE/256, 256, 0, stream>>>(idx_i, counts, rank);
    scan_kernel<<<1, 1024, 0, stream>>>(counts, start);
    pack_kernel<<<NE/256, 256, 0, stream>>>(f_ij, rcut, Yr, idx_i, idx_j,
                                            mW1, mb1, start, rank, epack);
    embed_kernel<<<NN/256, 256, 0, stream>>>(x, W1s, W1v, embed);
    nodeagg_kernel<<<NN/8, 256, 0, stream>>>(embed, epack, start, mW2, mb2, acc);
    out_kernel<<<NN/64, 256, 0, stream>>>(acc, W2s, W2v, W3s, W3v, out);
}

// Round 6
// 333.651 us; speedup vs baseline: 1.3848x; 1.2445x over previous
//
#include <hip/hip_runtime.h>
#include <math.h>

#define NN 32768
#define NE 524288
#define RSTR 32   // record stride in floats (128 B, cache-line aligned)
#define SREC_STR 36  // LDS record stride (floats): 4*r mod 32 tiles banks

// overflow-safe softplus(x) - ln2 using HW exp2/log2 (v_exp_f32 / v_log_f32)
__device__ __forceinline__ float sspf(float x) {
    const float INVLN2 = 1.4426950408889634f;
    const float LN2    = 0.69314718055994530942f;
    float t = __builtin_amdgcn_exp2f(-fabsf(x) * INVLN2);
    return fmaxf(x, 0.0f) + LN2 * __builtin_amdgcn_logf(1.0f + t) - LN2;
}

// ---------------- CSR build ----------------
// rank[e] = arrival order of edge e within its segment (atomic return).
__global__ __launch_bounds__(256) void hist_kernel(
    const int* __restrict__ idx_i, int* __restrict__ counts, int* __restrict__ rank)
{
    int e = blockIdx.x * 256 + threadIdx.x;
    rank[e] = atomicAdd(&counts[idx_i[e]], 1);
}

// single block, 1024 threads, 32 counts each; writes start[0..NN] and a
// degree-sorted (descending) node order for nodeagg load balance.
__global__ __launch_bounds__(1024) void scan_kernel(
    const int* __restrict__ counts, int* __restrict__ start, int* __restrict__ order)
{
    __shared__ int tmp[1024];
    __shared__ int bins[64];
    __shared__ int bcur[64];
    int tid = threadIdx.x;
    int base = tid * 32;
    int cnt[32];
    int local[32];
    int sum = 0;
    const int4* c4 = (const int4*)(counts + base);
#pragma unroll
    for (int q = 0; q < 8; q++) {
        int4 v = c4[q];
        cnt[q*4+0] = v.x; cnt[q*4+1] = v.y; cnt[q*4+2] = v.z; cnt[q*4+3] = v.w;
        local[q*4+0] = sum; sum += v.x;
        local[q*4+1] = sum; sum += v.y;
        local[q*4+2] = sum; sum += v.z;
        local[q*4+3] = sum; sum += v.w;
    }
    tmp[tid] = sum;
    __syncthreads();
    for (int off = 1; off < 1024; off <<= 1) {
        int v = 0;
        if (tid >= off) v = tmp[tid - off];
        __syncthreads();
        if (tid >= off) tmp[tid] += v;
        __syncthreads();
    }
    int excl = tmp[tid] - sum;
#pragma unroll
    for (int k = 0; k < 32; k++) {
        start[base + k] = excl + local[k];
    }
    if (tid == 1023) start[NN] = tmp[1023];

    // ---- descending-degree counting sort -> order[] ----
    if (tid < 64) bins[tid] = 0;
    __syncthreads();
#pragma unroll
    for (int k = 0; k < 32; k++) {
        int d = cnt[k] > 63 ? 63 : cnt[k];
        atomicAdd(&bins[63 - d], 1);
    }
    __syncthreads();
    if (tid == 0) {
        int run = 0;
        for (int b = 0; b < 64; b++) { int c = bins[b]; bcur[b] = run; run += c; }
    }
    __syncthreads();
#pragma unroll
    for (int k = 0; k < 32; k++) {
        int d = cnt[k] > 63 ? 63 : cnt[k];
        int pos = atomicAdd(&bcur[63 - d], 1);
        order[pos] = base + k;
    }
}

// ---------------- pack: fused fill + filter-MLP-layer-1 ----------------
// record (32 floats = one 128B line): [0:16)=h*rc, [16:20)=Yr, [20]=rc,
// [21]=j(bits), [22:32)=zero pad.
// Wave-cooperative scatter: records staged in LDS, then 8 lanes emit the 8
// float4 quarters of ONE record per store instruction -> each instruction
// writes 8 complete 128B lines (vs 64 partial lines in the naive scatter).
__global__ __launch_bounds__(256) void pack_kernel(
    const float* __restrict__ f_ij,     // (E,32)
    const float* __restrict__ rcut_ij,  // (E,)
    const float* __restrict__ Yr,       // (E,4)
    const int*   __restrict__ idx_i,
    const int*   __restrict__ idx_j,
    const float* __restrict__ mW1,      // (32,16)
    const float* __restrict__ mb1,      // (16,)
    const int*   __restrict__ start,    // (N+1,)
    const int*   __restrict__ rank,     // (E,)
    float* __restrict__ epack)
{
    __shared__ float sW1[512];
    __shared__ float sb1[16];
    __shared__ float srec[256 * SREC_STR];  // 36 KB
    __shared__ int   sslot[256];
    int t = threadIdx.x;
    for (int k = t; k < 512; k += 256) sW1[k] = mW1[k];
    if (t < 16) sb1[t] = mb1[t];
    __syncthreads();

    int e = blockIdx.x * 256 + t;
    float h[16];
#pragma unroll
    for (int f = 0; f < 16; f++) h[f] = sb1[f];
    const float4* frow = (const float4*)(f_ij + (size_t)e * 32);
#pragma unroll
    for (int rq = 0; rq < 8; rq++) {
        float4 fv = frow[rq];
        int r = rq * 4;
#pragma unroll
        for (int f = 0; f < 16; f++)
            h[f] += fv.x * sW1[(r+0)*16+f] + fv.y * sW1[(r+1)*16+f]
                  + fv.z * sW1[(r+2)*16+f] + fv.w * sW1[(r+3)*16+f];
    }
    float rc = rcut_ij[e];
#pragma unroll
    for (int f = 0; f < 16; f++) h[f] = sspf(h[f]) * rc;

    int i = idx_i[e];
    int j = idx_j[e];
    float4 y = ((const float4*)Yr)[e];
    int slot = start[i] + rank[e];

    // stage record in LDS
    float* rp = srec + t * SREC_STR;
    float4* rp4 = (float4*)rp;
#pragma unroll
    for (int q = 0; q < 4; q++) rp4[q] = ((float4*)h)[q];
    rp4[4] = y;
    float4 tail; tail.x = rc; tail.y = __int_as_float(j); tail.z = 0.f; tail.w = 0.f;
    rp4[5] = tail;
    float4 z; z.x = 0.f; z.y = 0.f; z.z = 0.f; z.w = 0.f;
    rp4[6] = z;
    rp4[7] = z;
    sslot[t] = slot;
    __syncthreads();

    // cooperative write: per instruction, lanes 0-7 cover record r0, lanes
    // 8-15 record r0+1, ... -> 8 full 128B lines per global_store_dwordx4.
    int lane = t & 63;
    int wbase = t & 192;          // wave's record base within block
    int qi = lane & 7;            // float4 quarter within record
#pragma unroll
    for (int g = 0; g < 8; g++) {
        int r = wbase + g * 8 + (lane >> 3);
        int s = sslot[r];
        float4 v = ((const float4*)(srec + r * SREC_STR))[qi];
        ((float4*)(epack + (size_t)s * RSTR))[qi] = v;
    }
}

// ---------------- node embedding ----------------
// interleaved output layout: embed[n*64 + f*4 + {0,1,2,3}] = {s1, v1x, v1y, v1z}
// so nodeagg fetches one float4 per (edge, lane).
// Staging loops are CHUNKED (#pragma unroll 1) to cap live registers.
__global__ __launch_bounds__(256) void embed_kernel(
    const float* __restrict__ x,
    const float* __restrict__ W1s,   // (64,16)
    const float* __restrict__ W1v,   // (32,16)
    float* __restrict__ embed)
{
    __shared__ float sWs[1024];
    __shared__ float sWv[512];
    int t = threadIdx.x;
    for (int k = t; k < 1024; k += 256) sWs[k] = W1s[k];
    for (int k = t; k < 512;  k += 256) sWv[k] = W1v[k];
    __syncthreads();

    int n = blockIdx.x * 256 + t;
    const float* xr = x + (size_t)n * 160;

    float s1[16];
#pragma unroll
    for (int f = 0; f < 16; f++) s1[f] = 0.f;
#pragma unroll 1
    for (int cc = 0; cc < 4; cc++) {
        float4 sv[4];
#pragma unroll
        for (int q = 0; q < 4; q++) sv[q] = ((const float4*)xr)[cc*4 + q];
#pragma unroll
        for (int q = 0; q < 4; q++) {
            int c = (cc*4 + q) * 4;
#pragma unroll
            for (int f = 0; f < 16; f++) {
                s1[f] += sv[q].x * sWs[(c+0)*16+f] + sv[q].y * sWs[(c+1)*16+f]
                       + sv[q].z * sWs[(c+2)*16+f] + sv[q].w * sWs[(c+3)*16+f];
            }
        }
    }

    float v1[48];
#pragma unroll
    for (int k = 0; k < 48; k++) v1[k] = 0.f;
    // 96 vector components = 4 chunks x 24 (= 8 columns x 3 dims each chunk)
#pragma unroll 1
    for (int cc = 0; cc < 4; cc++) {
        float4 vv[6];
#pragma unroll
        for (int q = 0; q < 6; q++) vv[q] = ((const float4*)(xr + 64))[cc*6 + q];
#pragma unroll
        for (int q = 0; q < 6; q++) {
            float vals[4] = {vv[q].x, vv[q].y, vv[q].z, vv[q].w};
#pragma unroll
            for (int u = 0; u < 4; u++) {
                int ml = q * 4 + u;         // 0..23, static
                int c = cc * 8 + ml / 3;    // runtime base + static
                int d = ml % 3;             // static
                float val = vals[u];
#pragma unroll
                for (int f = 0; f < 16; f++)
                    v1[f*3+d] += val * sWv[c*16+f];
            }
        }
    }

    float ob[64];
    const float is32 = 0.17677669529663688f;
#pragma unroll
    for (int f = 0; f < 16; f++) {
        ob[f*4+0] = s1[f] * 0.125f;
        ob[f*4+1] = v1[f*3+0] * is32;
        ob[f*4+2] = v1[f*3+1] * is32;
        ob[f*4+3] = v1[f*3+2] * is32;
    }

    float4* eo = (float4*)(embed + (size_t)n * 64);
#pragma unroll
    for (int q = 0; q < 16; q++) eo[q] = ((float4*)ob)[q];
}

// ---------------- node-centric aggregation ----------------
// 16 threads per node (4 nodes per wave), thread owns a single f.
// __launch_bounds__(256,4) -> 128-VGPR budget so the 64 per-thread weights
// live in REGISTERS (round-2 structure was LDS-reread-bound at VGPR=64).
// Nodes are processed in descending-degree order (order[]) so the 4 nodes
// sharing a wave have matched trip counts (minimal masked-lane waste).
// acc planar layout per node:
// [0:16)=n0a, [16:32)=n0b, [32:48)=n1a_x, [48:64)=n1a_y, [64:80)=n1a_z,
// [80:96)=n1b_x, [96:112)=n1b_y, [112:128)=n1b_z
__global__ __launch_bounds__(256, 4) void nodeagg_kernel(
    const float* __restrict__ embed,   // (N,64) interleaved (f*4+{s,x,y,z})
    const float* __restrict__ epack,   // (E,RSTR) CSR-ordered records
    const int*   __restrict__ start,   // (N+1,)
    const int*   __restrict__ order,   // (N,) degree-sorted node ids
    const float* __restrict__ mW2,     // (16,96)
    const float* __restrict__ mb2,     // (96,)
    float* __restrict__ acc)           // (N,128) planar
{
    int t = threadIdx.x;
    int gid = blockIdx.x * 256 + t;
    int node = order[gid >> 4];
    int f = gid & 15;

    float wga[16], wgb[16], wgc[16], wgd[16];
#pragma unroll
    for (int k = 0; k < 16; k++) {
        wga[k] = mW2[k*96 + f];
        wgb[k] = mW2[k*96 + 16 + f];
        wgc[k] = mW2[k*96 + 32 + f];
        wgd[k] = mW2[k*96 + 48 + f];
    }
    float b0a = mb2[f], b0b = mb2[16+f], b1a = mb2[32+f], b1b = mb2[48+f];

    float aa = 0.f, ab = 0.f;
    float A1a0 = 0.f, A1a1 = 0.f, A1a2 = 0.f;
    float A1b0 = 0.f, A1b1 = 0.f, A1b2 = 0.f;

    int s0 = start[node];
    int s1 = start[node+1];

    for (int q = s0; q < s1; q++) {
        const float4* r4 = (const float4*)(epack + (size_t)q * RSTR);
        float4 h0 = r4[0], h1 = r4[1], h2 = r4[2], h3 = r4[3];
        float4 y  = r4[4], tl = r4[5];
        int j = __float_as_int(tl.y);
        float4 e4 = ((const float4*)(embed + (size_t)j * 64))[f];
        float rc = tl.x;

        float w0a = rc*b0a, w0b = rc*b0b, w1a = rc*b1a, w1b = rc*b1b;
        w0a += h0.x*wga[0]  + h0.y*wga[1]  + h0.z*wga[2]  + h0.w*wga[3]
             + h1.x*wga[4]  + h1.y*wga[5]  + h1.z*wga[6]  + h1.w*wga[7]
             + h2.x*wga[8]  + h2.y*wga[9]  + h2.z*wga[10] + h2.w*wga[11]
             + h3.x*wga[12] + h3.y*wga[13] + h3.z*wga[14] + h3.w*wga[15];
        w0b += h0.x*wgb[0]  + h0.y*wgb[1]  + h0.z*wgb[2]  + h0.w*wgb[3]
             + h1.x*wgb[4]  + h1.y*wgb[5]  + h1.z*wgb[6]  + h1.w*wgb[7]
             + h2.x*wgb[8]  + h2.y*wgb[9]  + h2.z*wgb[10] + h2.w*wgb[11]
             + h3.x*wgb[12] + h3.y*wgb[13] + h3.z*wgb[14] + h3.w*wgb[15];
        w1a += h0.x*wgc[0]  + h0.y*wgc[1]  + h0.z*wgc[2]  + h0.w*wgc[3]
             + h1.x*wgc[4]  + h1.y*wgc[5]  + h1.z*wgc[6]  + h1.w*wgc[7]
             + h2.x*wgc[8]  + h2.y*wgc[9]  + h2.z*wgc[10] + h2.w*wgc[11]
             + h3.x*wgc[12] + h3.y*wgc[13] + h3.z*wgc[14] + h3.w*wgc[15];
        w1b += h0.x*wgd[0]  + h0.y*wgd[1]  + h0.z*wgd[2]  + h0.w*wgd[3]
             + h1.x*wgd[4]  + h1.y*wgd[5]  + h1.z*wgd[6]  + h1.w*wgd[7]
             + h2.x*wgd[8]  + h2.y*wgd[9]  + h2.z*wgd[10] + h2.w*wgd[11]
             + h3.x*wgd[12] + h3.y*wgd[13] + h3.z*wgd[14] + h3.w*wgd[15];

        float sj = e4.x, vx = e4.y, vy = e4.z, vz = e4.w;
        aa += sj * y.x * w0a;
        ab += (vx*y.y + vy*y.z + vz*y.w) * w0b;
        float sw = sj * w1a;
        A1a0 += sw * y.y;
        A1a1 += sw * y.z;
        A1a2 += sw * y.w;
        float yw = y.x * w1b;
        A1b0 += vx * yw;
        A1b1 += vy * yw;
        A1b2 += vz * yw;
    }

    const float is3 = 0.5773502691896258f;   // 1/sqrt(3)
    float* o = acc + (size_t)node * 128;
    o[f]       = aa;
    o[16 + f]  = ab * is3;
    o[32 + f]  = A1a0;
    o[48 + f]  = A1a1;
    o[64 + f]  = A1a2;
    o[80 + f]  = A1b0;
    o[96 + f]  = A1b1;
    o[112 + f] = A1b2;
}

// ---------------- node output ----------------
// 64 nodes per block (lane = node), 4 wave-specialized roles:
// wave 0: s-chain cols 0-31; wave 1: s-chain cols 32-63
// wave 2: v-chain (d=0 all cols, d=1 cols 0-15); wave 3: (d=1 cols 16-31, d=2 all)
// Weight columns are wave-uniform (readfirstlane) -> scalar s_load broadcasts.
// Intermediates in LDS with +1 pad (2-way bank alias only, free).

__device__ __forceinline__ void v2_seg32(const float* a, int d, int cb,
    const float* __restrict__ W2v, float* V2, int ln)
{
    cb = __builtin_amdgcn_readfirstlane(cb);
    const float is32 = 0.17677669529663688f;
    float na[16], nb[16];
    const float4* pa = (const float4*)(a + 32 + 16*d);
    const float4* pb = (const float4*)(a + 80 + 16*d);
#pragma unroll
    for (int q = 0; q < 4; q++) { ((float4*)na)[q] = pa[q]; ((float4*)nb)[q] = pb[q]; }
    float tacc[32];
#pragma unroll
    for (int c = 0; c < 32; c++) tacc[c] = 0.f;
#pragma unroll
    for (int f = 0; f < 16; f++) {
        float fa = na[f], fb = nb[f];
#pragma unroll
        for (int c = 0; c < 32; c++)
            tacc[c] += fa * W2v[f*32 + cb + c] + fb * W2v[(16+f)*32 + cb + c];
    }
    float* row = V2 + (d*64 + ln) * 33 + cb;
#pragma unroll
    for (int c = 0; c < 32; c++) row[c] = tacc[c] * is32;
}

__device__ __forceinline__ void v2_seg16(const float* a, int d, int cb,
    const float* __restrict__ W2v, float* V2, int ln)
{
    cb = __builtin_amdgcn_readfirstlane(cb);
    const float is32 = 0.17677669529663688f;
    float na[16], nb[16];
    const float4* pa = (const float4*)(a + 32 + 16*d);
    const float4* pb = (const float4*)(a + 80 + 16*d);
#pragma unroll
    for (int q = 0; q < 4; q++) { ((float4*)na)[q] = pa[q]; ((float4*)nb)[q] = pb[q]; }
    float tacc[16];
#pragma unroll
    for (int c = 0; c < 16; c++) tacc[c] = 0.f;
#pragma unroll
    for (int f = 0; f < 16; f++) {
        float fa = na[f], fb = nb[f];
#pragma unroll
        for (int c = 0; c < 16; c++)
            tacc[c] += fa * W2v[f*32 + cb + c] + fb * W2v[(16+f)*32 + cb + c];
    }
    float* row = V2 + (d*64 + ln) * 33 + cb;
#pragma unroll
    for (int c = 0; c < 16; c++) row[c] = tacc[c] * is32;
}

__device__ __forceinline__ void v3_seg32(float* o, int d, int cb,
    const float* __restrict__ W3v, const float* V2, int ln)
{
    cb = __builtin_amdgcn_readfirstlane(cb);
    const float is32 = 0.17677669529663688f;
    float tacc[32];
#pragma unroll
    for (int c = 0; c < 32; c++) tacc[c] = 0.f;
    const float* row = V2 + (d*64 + ln) * 33;
#pragma unroll
    for (int k = 0; k < 32; k++) {
        float vk = row[k];
#pragma unroll
        for (int c = 0; c < 32; c++) tacc[c] += vk * W3v[k*32 + cb + c];
    }
#pragma unroll
    for (int c = 0; c < 32; c++) o[64 + (cb+c)*3 + d] = tacc[c] * is32;
}

__device__ __forceinline__ void v3_seg16(float* o, int d, int cb,
    const float* __restrict__ W3v, const float* V2, int ln)
{
    cb = __builtin_amdgcn_readfirstlane(cb);
    const float is32 = 0.17677669529663688f;
    float tacc[16];
#pragma unroll
    for (int c = 0; c < 16; c++) tacc[c] = 0.f;
    const float* row = V2 + (d*64 + ln) * 33;
#pragma unroll
    for (int k = 0; k < 32; k++) {
        float vk = row[k];
#pragma unroll
        for (int c = 0; c < 16; c++) tacc[c] += vk * W3v[k*32 + cb + c];
    }
#pragma unroll
    for (int c = 0; c < 16; c++) o[64 + (cb+c)*3 + d] = tacc[c] * is32;
}

__global__ __launch_bounds__(256) void out_kernel(
    const float* __restrict__ acc,      // (N,128) planar
    const float* __restrict__ W2s,      // (32,64)
    const float* __restrict__ W2v,      // (32,32)
    const float* __restrict__ W3s,      // (64,64)
    const float* __restrict__ W3v,      // (32,32)
    float* __restrict__ out)            // (N,160)
{
    __shared__ float S2[64*65];   // S2[ln*65 + c], c<64
    __shared__ float V2[3*64*33]; // V2[(d*64+ln)*33 + c], c<32
    int t = threadIdx.x;
    int w = t >> 6, ln = t & 63;
    int node = blockIdx.x * 64 + ln;
    const float* a = acc + (size_t)node * 128;
    float* o = out + (size_t)node * 160;
    const float is32 = 0.17677669529663688f;

    if (w < 2) {
        int cb = __builtin_amdgcn_readfirstlane(w * 32);
        float n0r[32];
#pragma unroll
        for (int q = 0; q < 8; q++) ((float4*)n0r)[q] = ((const float4*)a)[q];
        float tacc[32];
#pragma unroll
        for (int c = 0; c < 32; c++) tacc[c] = 0.f;
#pragma unroll
        for (int k = 0; k < 32; k++) {
            float nk = n0r[k];
#pragma unroll
            for (int c = 0; c < 32; c++) tacc[c] += nk * W2s[k*64 + cb + c];
        }
        float* row = S2 + ln*65 + cb;
#pragma unroll
        for (int c = 0; c < 32; c++) row[c] = sspf(tacc[c] * is32);
    } else if (w == 2) {
        v2_seg32(a, 0, 0,  W2v, V2, ln);
        v2_seg16(a, 1, 0,  W2v, V2, ln);
    } else {
        v2_seg16(a, 1, 16, W2v, V2, ln);
        v2_seg32(a, 2, 0,  W2v, V2, ln);
    }
    __syncthreads();
    if (w < 2) {
        int cb = __builtin_amdgcn_readfirstlane(w * 32);
        float tacc[32];
#pragma unroll
        for (int c = 0; c < 32; c++) tacc[c] = 0.f;
        const float* row = S2 + ln*65;
#pragma unroll
        for (int k = 0; k < 64; k++) {
            float sk = row[k];
#pragma unroll
            for (int c = 0; c < 32; c++) tacc[c] += sk * W3s[k*64 + cb + c];
        }
#pragma unroll
        for (int q = 0; q < 8; q++) {
            float4 r = {tacc[q*4+0]*0.125f, tacc[q*4+1]*0.125f,
                        tacc[q*4+2]*0.125f, tacc[q*4+3]*0.125f};
            ((float4*)(o + cb))[q] = r;
        }
    } else if (w == 2) {
        v3_seg32(o, 0, 0,  W3v, V2, ln);
        v3_seg16(o, 1, 0,  W3v, V2, ln);
    } else {
        v3_seg16(o, 1, 16, W3v, V2, ln);
        v3_seg32(o, 2, 0,  W3v, V2, ln);
    }
}

extern "C" void kernel_launch(void* const* d_in, const int* in_sizes, int n_in,
                              void* d_out, int out_size, void* d_ws, size_t ws_size,
                              hipStream_t stream) {
    const float* x     = (const float*)d_in[0];
    const float* f_ij  = (const float*)d_in[1];
    const float* rcut  = (const float*)d_in[2];
    const float* Yr    = (const float*)d_in[3];
    const float* W1s   = (const float*)d_in[4];
    const float* W1v   = (const float*)d_in[5];
    const float* mW1   = (const float*)d_in[6];
    const float* mb1   = (const float*)d_in[7];
    const float* mW2   = (const float*)d_in[8];
    const float* mb2   = (const float*)d_in[9];
    const float* W2s   = (const float*)d_in[10];
    const float* W2v   = (const float*)d_in[11];
    const float* W3s   = (const float*)d_in[12];
    const float* W3v   = (const float*)d_in[13];
    const int*   idx_i = (const int*)d_in[14];
    const int*   idx_j = (const int*)d_in[15];
    float* out = (float*)d_out;

    // workspace layout (floats)
    float* fws   = (float*)d_ws;
    float* embed = fws;                                  // N*64
    float* acc   = embed + (size_t)NN * 64;              // N*128
    float* epack = acc   + (size_t)NN * 128;             // E*RSTR
    int* ibase   = (int*)(epack + (size_t)NE * RSTR);
    int* counts  = ibase;                                // N
    int* start   = counts + NN;                          // N+1
    int* rank    = start + NN + 1;                       // E
    int* order   = rank + NE;                            // N

    hipMemsetAsync(counts, 0, (size_t)NN * sizeof(int), stream);
    hist_kernel<<<NE/256, 256, 0, stream>>>(idx_i, counts, rank);
    scan_kernel<<<1, 1024, 0, stream>>>(counts, start, order);
    pack_kernel<<<NE/256, 256, 0, stream>>>(f_ij, rcut, Yr, idx_i, idx_j,
                                            mW1, mb1, start, rank, epack);
    embed_kernel<<<NN/256, 256, 0, stream>>>(x, W1s, W1v, embed);
    nodeagg_kernel<<<(NN*16)/256, 256, 0, stream>>>(embed, epack, start, order,
                                                    mW2, mb2, acc);
    out_kernel<<<NN/64, 256, 0, stream>>>(acc, W2s, W2v, W3s, W3v, out);
}

// Round 7
// 320.735 us; speedup vs baseline: 1.4406x; 1.0403x over previous
//
#include <hip/hip_runtime.h>
#include <math.h>

#define NN 32768
#define NE 524288
#define RSTR 32   // record stride in floats (128 B, cache-line aligned)
#define SREC_STR 36  // LDS record stride (floats)

// overflow-safe softplus(x) - ln2 using HW exp2/log2 (v_exp_f32 / v_log_f32)
__device__ __forceinline__ float sspf(float x) {
    const float INVLN2 = 1.4426950408889634f;
    const float LN2    = 0.69314718055994530942f;
    float t = __builtin_amdgcn_exp2f(-fabsf(x) * INVLN2);
    return fmaxf(x, 0.0f) + LN2 * __builtin_amdgcn_logf(1.0f + t) - LN2;
}

// ---------------- CSR build ----------------
// rank[e] = arrival order of edge e within its segment (atomic return).
__global__ __launch_bounds__(256) void hist_kernel(
    const int* __restrict__ idx_i, int* __restrict__ counts, int* __restrict__ rank)
{
    int e = blockIdx.x * 256 + threadIdx.x;
    rank[e] = atomicAdd(&counts[idx_i[e]], 1);
}

// single block, 1024 threads, 32 counts each; writes start[0..NN] and a
// degree-sorted (descending) node order for nodeagg load balance.
__global__ __launch_bounds__(1024) void scan_kernel(
    const int* __restrict__ counts, int* __restrict__ start, int* __restrict__ order)
{
    __shared__ int tmp[1024];
    __shared__ int bins[64];
    __shared__ int bcur[64];
    int tid = threadIdx.x;
    int base = tid * 32;
    int cnt[32];
    int local[32];
    int sum = 0;
    const int4* c4 = (const int4*)(counts + base);
#pragma unroll
    for (int q = 0; q < 8; q++) {
        int4 v = c4[q];
        cnt[q*4+0] = v.x; cnt[q*4+1] = v.y; cnt[q*4+2] = v.z; cnt[q*4+3] = v.w;
        local[q*4+0] = sum; sum += v.x;
        local[q*4+1] = sum; sum += v.y;
        local[q*4+2] = sum; sum += v.z;
        local[q*4+3] = sum; sum += v.w;
    }
    tmp[tid] = sum;
    __syncthreads();
    for (int off = 1; off < 1024; off <<= 1) {
        int v = 0;
        if (tid >= off) v = tmp[tid - off];
        __syncthreads();
        if (tid >= off) tmp[tid] += v;
        __syncthreads();
    }
    int excl = tmp[tid] - sum;
#pragma unroll
    for (int k = 0; k < 32; k++) {
        start[base + k] = excl + local[k];
    }
    if (tid == 1023) start[NN] = tmp[1023];

    // ---- descending-degree counting sort -> order[] ----
    if (tid < 64) bins[tid] = 0;
    __syncthreads();
#pragma unroll
    for (int k = 0; k < 32; k++) {
        int d = cnt[k] > 63 ? 63 : cnt[k];
        atomicAdd(&bins[63 - d], 1);
    }
    __syncthreads();
    if (tid == 0) {
        int run = 0;
        for (int b = 0; b < 64; b++) { int c = bins[b]; bcur[b] = run; run += c; }
    }
    __syncthreads();
#pragma unroll
    for (int k = 0; k < 32; k++) {
        int d = cnt[k] > 63 ? 63 : cnt[k];
        int pos = atomicAdd(&bcur[63 - d], 1);
        order[pos] = base + k;
    }
}

// ---------------- pack: fused fill + filter-MLP-layer-1 ----------------
// record (32 floats = one 128B line): [0:16)=h*rc, [16:20)=Yr, [20]=rc,
// [21]=j(bits), [22:32)=zero pad.
// TWO-PHASE cooperative scatter (LDS halved vs one-phase -> ~6 blocks/CU):
// phase p stages 128 records in LDS, then all 256 threads emit them as
// full 128B lines (8 lanes cover the 8 float4 quarters of one record per
// store instruction -> 8 complete lines per global_store_dwordx4).
__global__ __launch_bounds__(256) void pack_kernel(
    const float* __restrict__ f_ij,     // (E,32)
    const float* __restrict__ rcut_ij,  // (E,)
    const float* __restrict__ Yr,       // (E,4)
    const int*   __restrict__ idx_i,
    const int*   __restrict__ idx_j,
    const float* __restrict__ mW1,      // (32,16)
    const float* __restrict__ mb1,      // (16,)
    const int*   __restrict__ start,    // (N+1,)
    const int*   __restrict__ rank,     // (E,)
    float* __restrict__ epack)
{
    __shared__ float sW1[512];
    __shared__ float sb1[16];
    __shared__ float srec[128 * SREC_STR];  // 18 KB
    __shared__ int   sslot[128];
    int t = threadIdx.x;
    for (int k = t; k < 512; k += 256) sW1[k] = mW1[k];
    if (t < 16) sb1[t] = mb1[t];
    __syncthreads();

    int e = blockIdx.x * 256 + t;
    float h[16];
#pragma unroll
    for (int f = 0; f < 16; f++) h[f] = sb1[f];
    const float4* frow = (const float4*)(f_ij + (size_t)e * 32);
#pragma unroll
    for (int rq = 0; rq < 8; rq++) {
        float4 fv = frow[rq];
        int r = rq * 4;
#pragma unroll
        for (int f = 0; f < 16; f++)
            h[f] += fv.x * sW1[(r+0)*16+f] + fv.y * sW1[(r+1)*16+f]
                  + fv.z * sW1[(r+2)*16+f] + fv.w * sW1[(r+3)*16+f];
    }
    float rc = rcut_ij[e];
#pragma unroll
    for (int f = 0; f < 16; f++) h[f] = sspf(h[f]) * rc;

    int i = idx_i[e];
    int j = idx_j[e];
    float4 y = ((const float4*)Yr)[e];
    int slot = start[i] + rank[e];

#pragma unroll 1
    for (int p = 0; p < 2; p++) {
        if ((t >> 7) == p) {
            int r = t & 127;
            float* rp = srec + r * SREC_STR;
            float4* rp4 = (float4*)rp;
#pragma unroll
            for (int q = 0; q < 4; q++) rp4[q] = ((float4*)h)[q];
            rp4[4] = y;
            float4 tail; tail.x = rc; tail.y = __int_as_float(j);
            tail.z = 0.f; tail.w = 0.f;
            rp4[5] = tail;
            float4 z; z.x = 0.f; z.y = 0.f; z.z = 0.f; z.w = 0.f;
            rp4[6] = z;
            rp4[7] = z;
            sslot[r] = slot;
        }
        __syncthreads();
        // 128 records x 8 quarters = 1024 float4s / 256 threads = 4 each
#pragma unroll
        for (int g = 0; g < 4; g++) {
            int idx = g * 256 + t;
            int r = idx >> 3;
            int qi = idx & 7;
            int s = sslot[r];
            float4 v = ((const float4*)(srec + r * SREC_STR))[qi];
            ((float4*)(epack + (size_t)s * RSTR))[qi] = v;
        }
        __syncthreads();   // srec reuse safe for next phase
    }
}

// ---------------- node embedding ----------------
// interleaved output layout: embed[n*64 + f*4 + {0,1,2,3}] = {s1, v1x, v1y, v1z}
// so nodeagg fetches one float4 per (edge, lane).
// Staging loops are CHUNKED (#pragma unroll 1) to cap live registers.
__global__ __launch_bounds__(256) void embed_kernel(
    const float* __restrict__ x,
    const float* __restrict__ W1s,   // (64,16)
    const float* __restrict__ W1v,   // (32,16)
    float* __restrict__ embed)
{
    __shared__ float sWs[1024];
    __shared__ float sWv[512];
    int t = threadIdx.x;
    for (int k = t; k < 1024; k += 256) sWs[k] = W1s[k];
    for (int k = t; k < 512;  k += 256) sWv[k] = W1v[k];
    __syncthreads();

    int n = blockIdx.x * 256 + t;
    const float* xr = x + (size_t)n * 160;

    float s1[16];
#pragma unroll
    for (int f = 0; f < 16; f++) s1[f] = 0.f;
#pragma unroll 1
    for (int cc = 0; cc < 4; cc++) {
        float4 sv[4];
#pragma unroll
        for (int q = 0; q < 4; q++) sv[q] = ((const float4*)xr)[cc*4 + q];
#pragma unroll
        for (int q = 0; q < 4; q++) {
            int c = (cc*4 + q) * 4;
#pragma unroll
            for (int f = 0; f < 16; f++) {
                s1[f] += sv[q].x * sWs[(c+0)*16+f] + sv[q].y * sWs[(c+1)*16+f]
                       + sv[q].z * sWs[(c+2)*16+f] + sv[q].w * sWs[(c+3)*16+f];
            }
        }
    }

    float v1[48];
#pragma unroll
    for (int k = 0; k < 48; k++) v1[k] = 0.f;
    // 96 vector components = 4 chunks x 24 (= 8 columns x 3 dims each chunk)
#pragma unroll 1
    for (int cc = 0; cc < 4; cc++) {
        float4 vv[6];
#pragma unroll
        for (int q = 0; q < 6; q++) vv[q] = ((const float4*)(xr + 64))[cc*6 + q];
#pragma unroll
        for (int q = 0; q < 6; q++) {
            float vals[4] = {vv[q].x, vv[q].y, vv[q].z, vv[q].w};
#pragma unroll
            for (int u = 0; u < 4; u++) {
                int ml = q * 4 + u;         // 0..23, static
                int c = cc * 8 + ml / 3;    // runtime base + static
                int d = ml % 3;             // static
                float val = vals[u];
#pragma unroll
                for (int f = 0; f < 16; f++)
                    v1[f*3+d] += val * sWv[c*16+f];
            }
        }
    }

    float ob[64];
    const float is32 = 0.17677669529663688f;
#pragma unroll
    for (int f = 0; f < 16; f++) {
        ob[f*4+0] = s1[f] * 0.125f;
        ob[f*4+1] = v1[f*3+0] * is32;
        ob[f*4+2] = v1[f*3+1] * is32;
        ob[f*4+3] = v1[f*3+2] * is32;
    }

    float4* eo = (float4*)(embed + (size_t)n * 64);
#pragma unroll
    for (int q = 0; q < 16; q++) eo[q] = ((float4*)ob)[q];
}

// ---------------- node-centric aggregation ----------------
// 16 threads per node (4 nodes per wave), thread owns a single f.
// __launch_bounds__(256,4) -> 128-VGPR budget so the 64 per-thread weights
// live in REGISTERS. Nodes processed in descending-degree order (order[]).
__global__ __launch_bounds__(256, 4) void nodeagg_kernel(
    const float* __restrict__ embed,   // (N,64) interleaved (f*4+{s,x,y,z})
    const float* __restrict__ epack,   // (E,RSTR) CSR-ordered records
    const int*   __restrict__ start,   // (N+1,)
    const int*   __restrict__ order,   // (N,) degree-sorted node ids
    const float* __restrict__ mW2,     // (16,96)
    const float* __restrict__ mb2,     // (96,)
    float* __restrict__ acc)           // (N,128) planar
{
    int t = threadIdx.x;
    int gid = blockIdx.x * 256 + t;
    int node = order[gid >> 4];
    int f = gid & 15;

    float wga[16], wgb[16], wgc[16], wgd[16];
#pragma unroll
    for (int k = 0; k < 16; k++) {
        wga[k] = mW2[k*96 + f];
        wgb[k] = mW2[k*96 + 16 + f];
        wgc[k] = mW2[k*96 + 32 + f];
        wgd[k] = mW2[k*96 + 48 + f];
    }
    float b0a = mb2[f], b0b = mb2[16+f], b1a = mb2[32+f], b1b = mb2[48+f];

    float aa = 0.f, ab = 0.f;
    float A1a0 = 0.f, A1a1 = 0.f, A1a2 = 0.f;
    float A1b0 = 0.f, A1b1 = 0.f, A1b2 = 0.f;

    int s0 = start[node];
    int s1 = start[node+1];

    for (int q = s0; q < s1; q++) {
        const float4* r4 = (const float4*)(epack + (size_t)q * RSTR);
        float4 h0 = r4[0], h1 = r4[1], h2 = r4[2], h3 = r4[3];
        float4 y  = r4[4], tl = r4[5];
        int j = __float_as_int(tl.y);
        float4 e4 = ((const float4*)(embed + (size_t)j * 64))[f];
        float rc = tl.x;

        float w0a = rc*b0a, w0b = rc*b0b, w1a = rc*b1a, w1b = rc*b1b;
        w0a += h0.x*wga[0]  + h0.y*wga[1]  + h0.z*wga[2]  + h0.w*wga[3]
             + h1.x*wga[4]  + h1.y*wga[5]  + h1.z*wga[6]  + h1.w*wga[7]
             + h2.x*wga[8]  + h2.y*wga[9]  + h2.z*wga[10] + h2.w*wga[11]
             + h3.x*wga[12] + h3.y*wga[13] + h3.z*wga[14] + h3.w*wga[15];
        w0b += h0.x*wgb[0]  + h0.y*wgb[1]  + h0.z*wgb[2]  + h0.w*wgb[3]
             + h1.x*wgb[4]  + h1.y*wgb[5]  + h1.z*wgb[6]  + h1.w*wgb[7]
             + h2.x*wgb[8]  + h2.y*wgb[9]  + h2.z*wgb[10] + h2.w*wgb[11]
             + h3.x*wgb[12] + h3.y*wgb[13] + h3.z*wgb[14] + h3.w*wgb[15];
        w1a += h0.x*wgc[0]  + h0.y*wgc[1]  + h0.z*wgc[2]  + h0.w*wgc[3]
             + h1.x*wgc[4]  + h1.y*wgc[5]  + h1.z*wgc[6]  + h1.w*wgc[7]
             + h2.x*wgc[8]  + h2.y*wgc[9]  + h2.z*wgc[10] + h2.w*wgc[11]
             + h3.x*wgc[12] + h3.y*wgc[13] + h3.z*wgc[14] + h3.w*wgc[15];
        w1b += h0.x*wgd[0]  + h0.y*wgd[1]  + h0.z*wgd[2]  + h0.w*wgd[3]
             + h1.x*wgd[4]  + h1.y*wgd[5]  + h1.z*wgd[6]  + h1.w*wgd[7]
             + h2.x*wgd[8]  + h2.y*wgd[9]  + h2.z*wgd[10] + h2.w*wgd[11]
             + h3.x*wgd[12] + h3.y*wgd[13] + h3.z*wgd[14] + h3.w*wgd[15];

        float sj = e4.x, vx = e4.y, vy = e4.z, vz = e4.w;
        aa += sj * y.x * w0a;
        ab += (vx*y.y + vy*y.z + vz*y.w) * w0b;
        float sw = sj * w1a;
        A1a0 += sw * y.y;
        A1a1 += sw * y.z;
        A1a2 += sw * y.w;
        float yw = y.x * w1b;
        A1b0 += vx * yw;
        A1b1 += vy * yw;
        A1b2 += vz * yw;
    }

    const float is3 = 0.5773502691896258f;   // 1/sqrt(3)
    float* o = acc + (size_t)node * 128;
    o[f]       = aa;
    o[16 + f]  = ab * is3;
    o[32 + f]  = A1a0;
    o[48 + f]  = A1a1;
    o[64 + f]  = A1a2;
    o[80 + f]  = A1b0;
    o[96 + f]  = A1b1;
    o[112 + f] = A1b2;
}

// ---------------- node output ----------------
// 64 nodes per block (lane = node), 512 threads = 8 waves (balanced roles):
// waves 0-3: s-chain, 16 cols each (s2 k=32, s3 k=64)
// waves 4-7: v-chain, 24 col-dims each over flattened cd = d*32+c
// Weight addresses wave-uniform (readfirstlane) -> scalar broadcast loads.
// Intermediates in LDS, odd strides (65/33) -> <=2-way aliasing (free).

template<int LEN>
__device__ __forceinline__ void v2_seg(const float* a, int d, int cb,
    const float* __restrict__ W2v, float* V2, int ln)
{
    cb = __builtin_amdgcn_readfirstlane(cb);
    d  = __builtin_amdgcn_readfirstlane(d);
    const float is32 = 0.17677669529663688f;
    float na[16], nb[16];
    const float4* pa = (const float4*)(a + 32 + 16*d);
    const float4* pb = (const float4*)(a + 80 + 16*d);
#pragma unroll
    for (int q = 0; q < 4; q++) { ((float4*)na)[q] = pa[q]; ((float4*)nb)[q] = pb[q]; }
    float tacc[LEN];
#pragma unroll
    for (int c = 0; c < LEN; c++) tacc[c] = 0.f;
#pragma unroll
    for (int f = 0; f < 16; f++) {
        float fa = na[f], fb = nb[f];
#pragma unroll
        for (int c = 0; c < LEN; c++)
            tacc[c] += fa * W2v[f*32 + cb + c] + fb * W2v[(16+f)*32 + cb + c];
    }
    float* row = V2 + (d*64 + ln) * 33 + cb;
#pragma unroll
    for (int c = 0; c < LEN; c++) row[c] = tacc[c] * is32;
}

template<int LEN>
__device__ __forceinline__ void v3_seg(float* o, int d, int cb,
    const float* __restrict__ W3v, const float* V2, int ln)
{
    cb = __builtin_amdgcn_readfirstlane(cb);
    d  = __builtin_amdgcn_readfirstlane(d);
    const float is32 = 0.17677669529663688f;
    float tacc[LEN];
#pragma unroll
    for (int c = 0; c < LEN; c++) tacc[c] = 0.f;
    const float* row = V2 + (d*64 + ln) * 33;
#pragma unroll
    for (int k = 0; k < 32; k++) {
        float vk = row[k];
#pragma unroll
        for (int c = 0; c < LEN; c++) tacc[c] += vk * W3v[k*32 + cb + c];
    }
#pragma unroll
    for (int c = 0; c < LEN; c++) o[64 + (cb+c)*3 + d] = tacc[c] * is32;
}

__global__ __launch_bounds__(512, 4) void out_kernel(
    const float* __restrict__ acc,      // (N,128) planar
    const float* __restrict__ W2s,      // (32,64)
    const float* __restrict__ W2v,      // (32,32)
    const float* __restrict__ W3s,      // (64,64)
    const float* __restrict__ W3v,      // (32,32)
    float* __restrict__ out)            // (N,160)
{
    __shared__ float S2[64*65];   // S2[ln*65 + c], c<64
    __shared__ float V2[3*64*33]; // V2[(d*64+ln)*33 + c], c<32
    int t = threadIdx.x;
    int w = t >> 6, ln = t & 63;
    int node = blockIdx.x * 64 + ln;
    const float* a = acc + (size_t)node * 128;
    float* o = out + (size_t)node * 160;
    const float is32 = 0.17677669529663688f;

    if (w < 4) {
        int cb = __builtin_amdgcn_readfirstlane(w * 16);
        float n0r[32];
#pragma unroll
        for (int q = 0; q < 8; q++) ((float4*)n0r)[q] = ((const float4*)a)[q];
        float tacc[16];
#pragma unroll
        for (int c = 0; c < 16; c++) tacc[c] = 0.f;
#pragma unroll
        for (int k = 0; k < 32; k++) {
            float nk = n0r[k];
#pragma unroll
            for (int c = 0; c < 16; c++) tacc[c] += nk * W2s[k*64 + cb + c];
        }
        float* row = S2 + ln*65 + cb;
#pragma unroll
        for (int c = 0; c < 16; c++) row[c] = sspf(tacc[c] * is32);
    } else if (w == 4) {
        v2_seg<24>(a, 0, 0,  W2v, V2, ln);
    } else if (w == 5) {
        v2_seg<8> (a, 0, 24, W2v, V2, ln);
        v2_seg<16>(a, 1, 0,  W2v, V2, ln);
    } else if (w == 6) {
        v2_seg<16>(a, 1, 16, W2v, V2, ln);
        v2_seg<8> (a, 2, 0,  W2v, V2, ln);
    } else {
        v2_seg<24>(a, 2, 8,  W2v, V2, ln);
    }
    __syncthreads();
    if (w < 4) {
        int cb = __builtin_amdgcn_readfirstlane(w * 16);
        float tacc[16];
#pragma unroll
        for (int c = 0; c < 16; c++) tacc[c] = 0.f;
        const float* row = S2 + ln*65;
#pragma unroll
        for (int k = 0; k < 64; k++) {
            float sk = row[k];
#pragma unroll
            for (int c = 0; c < 16; c++) tacc[c] += sk * W3s[k*64 + cb + c];
        }
#pragma unroll
        for (int q = 0; q < 4; q++) {
            float4 r = {tacc[q*4+0]*0.125f, tacc[q*4+1]*0.125f,
                        tacc[q*4+2]*0.125f, tacc[q*4+3]*0.125f};
            ((float4*)(o + cb))[q] = r;
        }
    } else if (w == 4) {
        v3_seg<24>(o, 0, 0,  W3v, V2, ln);
    } else if (w == 5) {
        v3_seg<8> (o, 0, 24, W3v, V2, ln);
        v3_seg<16>(o, 1, 0,  W3v, V2, ln);
    } else if (w == 6) {
        v3_seg<16>(o, 1, 16, W3v, V2, ln);
        v3_seg<8> (o, 2, 0,  W3v, V2, ln);
    } else {
        v3_seg<24>(o, 2, 8,  W3v, V2, ln);
    }
}

extern "C" void kernel_launch(void* const* d_in, const int* in_sizes, int n_in,
                              void* d_out, int out_size, void* d_ws, size_t ws_size,
                              hipStream_t stream) {
    const float* x     = (const float*)d_in[0];
    const float* f_ij  = (const float*)d_in[1];
    const float* rcut  = (const float*)d_in[2];
    const float* Yr    = (const float*)d_in[3];
    const float* W1s   = (const float*)d_in[4];
    const float* W1v   = (const float*)d_in[5];
    const float* mW1   = (const float*)d_in[6];
    const float* mb1   = (const float*)d_in[7];
    const float* mW2   = (const float*)d_in[8];
    const float* mb2   = (const float*)d_in[9];
    const float* W2s   = (const float*)d_in[10];
    const float* W2v   = (const float*)d_in[11];
    const float* W3s   = (const float*)d_in[12];
    const float* W3v   = (const float*)d_in[13];
    const int*   idx_i = (const int*)d_in[14];
    const int*   idx_j = (const int*)d_in[15];
    float* out = (float*)d_out;

    // workspace layout (floats)
    float* fws   = (float*)d_ws;
    float* embed = fws;                                  // N*64
    float* acc   = embed + (size_t)NN * 64;              // N*128
    float* epack = acc   + (size_t)NN * 128;             // E*RSTR
    int* ibase   = (int*)(epack + (size_t)NE * RSTR);
    int* counts  = ibase;                                // N
    int* start   = counts + NN;                          // N+1
    int* rank    = start + NN + 1;                       // E
    int* order   = rank + NE;                            // N

    hipMemsetAsync(counts, 0, (size_t)NN * sizeof(int), stream);
    hist_kernel<<<NE/256, 256, 0, stream>>>(idx_i, counts, rank);
    scan_kernel<<<1, 1024, 0, stream>>>(counts, start, order);
    pack_kernel<<<NE/256, 256, 0, stream>>>(f_ij, rcut, Yr, idx_i, idx_j,
                                            mW1, mb1, start, rank, epack);
    embed_kernel<<<NN/256, 256, 0, stream>>>(x, W1s, W1v, embed);
    nodeagg_kernel<<<(NN*16)/256, 256, 0, stream>>>(embed, epack, start, order,
                                                    mW2, mb2, acc);
    out_kernel<<<NN/64, 512, 0, stream>>>(acc, W2s, W2v, W3s, W3v, out);
}